// Round 1
// baseline (3673.759 us; speedup 1.0000x reference)
//
#include <hip/hip_runtime.h>
#include <stdint.h>

// EISepLSTM: x(T,B,I) -> ig GEMM -> 512-step EI recurrence -> out GEMM.
// T=512, B=128, I=H=O=512.
// Recurrence: 32 blocks = 8 batch-groups (M=16) x 4 H-chunks (N=128).
// Wrec chunk register-resident per wave (32 cols x 512 k bf16 = 128 VGPR).
// Per-step h exchange between the 4 sibling blocks via MALL (agent-scope
// atomics + flag counters). All 32 blocks co-resident (grid << 256 CUs).

typedef __attribute__((ext_vector_type(8))) short short8;
typedef __attribute__((ext_vector_type(4))) float f32x4;

__device__ __forceinline__ unsigned short f2b(float f) {
  unsigned int u = __float_as_uint(f);
  u = (u + 0x7fffu + ((u >> 16) & 1u)) >> 16;   // RNE
  return (unsigned short)u;
}
__device__ __forceinline__ float b2f(unsigned short s) {
  return __uint_as_float(((unsigned int)s) << 16);
}

// ---------------- prep: ei table, bf16 weight casts, c_last zeros ----------
__global__ void prep_kernel(const float* __restrict__ gu,      // (T,H,2)
                            const float* __restrict__ logit,   // (H,2)
                            const float* __restrict__ wrec,    // (H,H)
                            const float* __restrict__ win,     // (H,I)
                            const float* __restrict__ wout,    // (O,H)
                            float* __restrict__ ei,            // (T,H)
                            unsigned short* __restrict__ wrecb,
                            unsigned short* __restrict__ winb,
                            unsigned short* __restrict__ woutb,
                            float* __restrict__ c_last) {
  int i = blockIdx.x * 256 + threadIdx.x;          // 0 .. 262143
  int h = i & 511;
  float u0 = gu[2 * i], u1 = gu[2 * i + 1];
  float l0 = logit[2 * h], l1 = logit[2 * h + 1];
  float g0 = -logf(-logf(u0 + 1e-10f) + 1e-10f);
  float g1 = -logf(-logf(u1 + 1e-10f) + 1e-10f);
  // softmax2 diff == tanh(dz/2), dz = ((l0+g0)-(l1+g1))/tau
  float dz = ((l0 + g0) - (l1 + g1)) * 10.0f;
  ei[i] = tanhf(0.5f * dz);
  wrecb[i] = f2b(fmaxf(wrec[i], 0.0f));
  winb[i]  = f2b(win[i]);
  woutb[i] = f2b(wout[i]);
  if (i < 65536) c_last[i] = 0.0f;
}

// ---------------- GEMM: C[m,n] = sum_k A[m,k]*W[n,k] + bias[n] -------------
// A: M x 512 (f32 or bf16), W: 512 x 512 bf16 row-major, out f32 or bf16.
// 128x128 tile, BK=32, 4 waves each 64x64. Swizzled LDS (2-way max).
template <int A_F32, int OUT_BF16>
__global__ __launch_bounds__(256, 2) void gemm512(
    const void* __restrict__ Ap, const unsigned short* __restrict__ W,
    const float* __restrict__ bias, void* __restrict__ Cp) {
  __shared__ __align__(16) unsigned short Al[128][32];
  __shared__ __align__(16) unsigned short Bl[128][32];
  const int tid = threadIdx.x;
  const int w = tid >> 6, l = tid & 63;
  const int wr = w >> 1, wc = w & 1;
  const int lm = l & 15, lq = l >> 4;
  const size_t m0 = (size_t)blockIdx.x * 128;
  const int n0 = blockIdx.y * 128;
  const int r = tid >> 1;             // staging row 0..127
  const int sb = (tid & 1) << 1;      // staging slot base (16B slots): 0 or 2
  f32x4 acc[4][4] = {};

  for (int kt = 0; kt < 16; ++kt) {
    const int k0 = kt << 5;
    // stage A tile
    {
      char* dst = (char*)Al + r * 64;
      if (A_F32) {
        const float* A = (const float*)Ap + (m0 + r) * 512 + k0 + (sb << 3);
#pragma unroll
        for (int j = 0; j < 2; ++j) {
          float4 v0 = ((const float4*)A)[2 * j + 0];
          float4 v1 = ((const float4*)A)[2 * j + 1];
          short8 o;
          o[0] = (short)f2b(v0.x); o[1] = (short)f2b(v0.y);
          o[2] = (short)f2b(v0.z); o[3] = (short)f2b(v0.w);
          o[4] = (short)f2b(v1.x); o[5] = (short)f2b(v1.y);
          o[6] = (short)f2b(v1.z); o[7] = (short)f2b(v1.w);
          *(short8*)(dst + (((sb + j + (r >> 1)) & 3) << 4)) = o;
        }
      } else {
        const unsigned short* A =
            (const unsigned short*)Ap + (m0 + r) * 512 + k0 + (sb << 3);
#pragma unroll
        for (int j = 0; j < 2; ++j)
          *(short8*)(dst + (((sb + j + (r >> 1)) & 3) << 4)) =
              *(const short8*)(A + 8 * j);
      }
      // stage W tile
      const unsigned short* Wp = W + ((size_t)(n0 + r) << 9) + k0 + (sb << 3);
      char* dstB = (char*)Bl + r * 64;
#pragma unroll
      for (int j = 0; j < 2; ++j)
        *(short8*)(dstB + (((sb + j + (r >> 1)) & 3) << 4)) =
            *(const short8*)(Wp + 8 * j);
    }
    __syncthreads();
    short8 af[4], bf[4];
#pragma unroll
    for (int i = 0; i < 4; ++i) {
      int row = wr * 64 + i * 16 + lm;
      af[i] = *(const short8*)((char*)Al + row * 64 +
                               (((lq + (row >> 1)) & 3) << 4));
    }
#pragma unroll
    for (int j = 0; j < 4; ++j) {
      int row = wc * 64 + j * 16 + lm;
      bf[j] = *(const short8*)((char*)Bl + row * 64 +
                               (((lq + (row >> 1)) & 3) << 4));
    }
#pragma unroll
    for (int i = 0; i < 4; ++i)
#pragma unroll
      for (int j = 0; j < 4; ++j)
        acc[i][j] =
            __builtin_amdgcn_mfma_f32_16x16x32_bf16(af[i], bf[j], acc[i][j], 0, 0, 0);
    __syncthreads();
  }
  float bv[4];
#pragma unroll
  for (int j = 0; j < 4; ++j) bv[j] = bias[n0 + wc * 64 + j * 16 + lm];
#pragma unroll
  for (int i = 0; i < 4; ++i) {
#pragma unroll
    for (int r4 = 0; r4 < 4; ++r4) {
      size_t gm = m0 + wr * 64 + i * 16 + lq * 4 + r4;
#pragma unroll
      for (int j = 0; j < 4; ++j) {
        int gn = n0 + wc * 64 + j * 16 + lm;
        float v = acc[i][j][r4] + bv[j];
        if (OUT_BF16)
          ((unsigned short*)Cp)[(gm << 9) + gn] = f2b(v);
        else
          ((float*)Cp)[(gm << 9) + gn] = v;
      }
    }
  }
}

// ---------------- recurrence ----------------------------------------------
// grid = 32: block = (group g = bid>>2) x (chunk = bid&3).
// group handles batches [16g,16g+16); chunk handles h-cols [128c,128c+128).
// 4 waves; wave owns 32 cols (2 n-tiles). Wrec rows for those cols live in
// registers (breg[16][2], 128 VGPR). a_t = h_t*ei_t staged in LDS (swizzled),
// own chunk written locally, siblings exchanged via hx in global + flags.
__global__ __launch_bounds__(256, 1) void recur_kernel(
    const unsigned short* __restrict__ ig,   // (T,B,H) bf16
    const float* __restrict__ ei,            // (T,H)
    const unsigned short* __restrict__ wrecb,// (H,H) bf16
    const float* __restrict__ rbias,         // (H)
    unsigned short* __restrict__ hs,         // (T,B,H) bf16 out
    unsigned short* __restrict__ hx,         // (2,B,H) bf16 exchange
    int* __restrict__ flags,                 // (8,512)
    float* __restrict__ h_last) {            // (B,H) f32 out
  __shared__ __align__(16) unsigned short Als[2][16][512];  // 32 KB
  const int tid = threadIdx.x;
  const int g = blockIdx.x >> 2, chunk = blockIdx.x & 3;
  const int bb = g << 4;
  const int w = tid >> 6, l = tid & 63;
  const int lm = l & 15, lq = l >> 4;
  const int nb0 = (chunk << 7) + (w << 5);
  const int n_0 = nb0 + lm, n_1 = nb0 + 16 + lm;

  // register-resident Wrec chunk: breg[kk][nt] = Wrec[n, kk*32 + lq*8 .. +8]
  short8 breg[16][2];
#pragma unroll
  for (int kk = 0; kk < 16; ++kk) {
    breg[kk][0] = *(const short8*)(wrecb + ((size_t)n_0 << 9) + (kk << 5) + (lq << 3));
    breg[kk][1] = *(const short8*)(wrecb + ((size_t)n_1 << 9) + (kk << 5) + (lq << 3));
  }
  const float rb0 = rbias[n_0], rb1 = rbias[n_1];
  const int sm = tid >> 4;      // staging row (batch) 0..15
  const int ss0 = tid & 15;     // staging slot low

#pragma unroll 1
  for (int t = 0; t < 512; ++t) {
    const int par = t & 1;
    const int par2 = (t + 1) & 1;
    // prefetch ig[t] for this lane's 8 (m,n) outputs
    unsigned short igv[2][4];
#pragma unroll
    for (int r4 = 0; r4 < 4; ++r4) {
      size_t rowb = ((size_t)(t << 7) + bb + (lq << 2) + r4) << 9;
      igv[0][r4] = __builtin_nontemporal_load(ig + rowb + n_0);
      igv[1][r4] = __builtin_nontemporal_load(ig + rowb + n_1);
    }
    float eiv0 = 0.f, eiv1 = 0.f;
    if (t < 511) {
      eiv0 = ei[((t + 1) << 9) + n_0];
      eiv1 = ei[((t + 1) << 9) + n_1];
    }
    f32x4 acc0 = {0.f, 0.f, 0.f, 0.f}, acc1 = {0.f, 0.f, 0.f, 0.f};
    if (t > 0) {
      if (tid == 0) {
        while (__hip_atomic_load(&flags[(g << 9) + t], __ATOMIC_RELAXED,
                                 __HIP_MEMORY_SCOPE_AGENT) < 4) {}
        __threadfence();
      }
      __syncthreads();
      // stage the 3 remote chunks of a_t into Als[par] (agent-coherent loads)
      {
        const unsigned int* src32 =
            (const unsigned int*)hx + (((size_t)(par * 128 + bb + sm)) << 8);
        char* dstbase = (char*)Als + par * 16384 + sm * 1024;
#pragma unroll
        for (int j = 0; j < 4; ++j) {
          if (j == chunk) continue;
          int s = ss0 + (j << 4);
          unsigned int* d = (unsigned int*)(dstbase + ((s ^ (sm & 7)) << 4));
#pragma unroll
          for (int q = 0; q < 4; ++q)
            d[q] = __hip_atomic_load(src32 + s * 4 + q, __ATOMIC_RELAXED,
                                     __HIP_MEMORY_SCOPE_AGENT);
        }
      }
      __syncthreads();
      // K-loop: rec = a_t @ Wrec_chunk^T
      const char* abase = (char*)Als + par * 16384 + lm * 1024;
#pragma unroll
      for (int kk = 0; kk < 16; ++kk) {
        short8 av = *(const short8*)(abase + ((((kk << 2) + lq) ^ (lm & 7)) << 4));
        acc0 = __builtin_amdgcn_mfma_f32_16x16x32_bf16(av, breg[kk][0], acc0, 0, 0, 0);
        acc1 = __builtin_amdgcn_mfma_f32_16x16x32_bf16(av, breg[kk][1], acc1, 0, 0, 0);
      }
    }
    // epilogue: h = softplus(acc + ig + rbias); emit hs, h_last, a_{t+1}
#pragma unroll
    for (int nt = 0; nt < 2; ++nt) {
      const int n = nt ? n_1 : n_0;
      const float rbv = nt ? rb1 : rb0;
      const float eivv = nt ? eiv1 : eiv0;
#pragma unroll
      for (int r4 = 0; r4 < 4; ++r4) {
        const int mm = (lq << 2) + r4;
        float z = (nt ? acc1[r4] : acc0[r4]) + b2f(igv[nt][r4]) + rbv;
        float h = (z > 20.f) ? z : log1pf(__expf(z));
        __builtin_nontemporal_store(
            f2b(h), hs + (((size_t)(t << 7) + bb + mm) << 9) + n);
        if (t == 511) {
          h_last[((bb + mm) << 9) + n] = h;
        } else {
          unsigned short a = f2b(h * eivv);
          // sibling-visible copy (agent-coherent store)
          __hip_atomic_store(hx + (((size_t)(par2 * 128 + bb + mm)) << 9) + n,
                             a, __ATOMIC_RELAXED, __HIP_MEMORY_SCOPE_AGENT);
          // own chunk straight into next LDS buffer (swizzled)
          *(unsigned short*)((char*)Als + par2 * 16384 + mm * 1024 +
                             ((((n >> 3) ^ (mm & 7)) << 4) | ((n & 7) << 1))) = a;
        }
      }
    }
    if (t < 511) {
      __syncthreads();   // all stores drained (vmcnt) before flag
      if (tid == 0) {
        __threadfence();
        __hip_atomic_fetch_add(&flags[(g << 9) + t + 1], 1, __ATOMIC_RELAXED,
                               __HIP_MEMORY_SCOPE_AGENT);
      }
    }
  }
}

// ---------------- launch ---------------------------------------------------
extern "C" void kernel_launch(void* const* d_in, const int* in_sizes, int n_in,
                              void* d_out, int out_size, void* d_ws,
                              size_t ws_size, hipStream_t stream) {
  const float* x     = (const float*)d_in[0];
  const float* gu    = (const float*)d_in[1];
  const float* Win   = (const float*)d_in[2];
  const float* bin   = (const float*)d_in[3];
  const float* Wrec  = (const float*)d_in[4];
  const float* rbias = (const float*)d_in[5];
  const float* elog  = (const float*)d_in[6];
  const float* Wout  = (const float*)d_in[7];
  const float* bout  = (const float*)d_in[8];

  char* ws = (char*)d_ws;
  int* flags            = (int*)ws;                                 // 16 KB
  float* ei             = (float*)(ws + 16384);                     // 1 MB
  unsigned short* wrecb = (unsigned short*)(ws + 1064960);          // 512 KB
  unsigned short* winb  = (unsigned short*)(ws + 1589248);          // 512 KB
  unsigned short* woutb = (unsigned short*)(ws + 2113536);          // 512 KB
  unsigned short* hx    = (unsigned short*)(ws + 2637824);          // 256 KB
  unsigned short* ig    = (unsigned short*)(ws + 2899968);          // 64 MB
  unsigned short* hs    = (unsigned short*)(ws + 70008832);         // 64 MB

  float* outp  = (float*)d_out;            // (T,B,O) f32
  float* hlast = outp + 33554432;          // (B,H)
  float* clast = outp + 33554432 + 65536;  // (B,H) zeros

  hipMemsetAsync(flags, 0, 16384, stream);
  prep_kernel<<<1024, 256, 0, stream>>>(gu, elog, Wrec, Win, Wout, ei, wrecb,
                                        winb, woutb, clast);
  gemm512<1, 1><<<dim3(512, 4), 256, 0, stream>>>(x, winb, bin, ig);
  recur_kernel<<<32, 256, 0, stream>>>(ig, ei, wrecb, rbias, hs, hx, flags,
                                       hlast);
  gemm512<0, 0><<<dim3(512, 4), 256, 0, stream>>>(hs, woutb, bout, outp);
}